// Round 1
// baseline (390.863 us; speedup 1.0000x reference)
//
#include <hip/hip_runtime.h>
#include <stdint.h>

// TF_MODE 0: jax_threefry_partitionable = True (JAX >= 0.4.36 default)
// TF_MODE 1: original (pre-partitionable) threefry split/random_bits
#ifndef TF_MODE
#define TF_MODE 0
#endif

namespace {

constexpr int H      = 32;    // LSTM_SIZE
constexpr int G4     = 128;   // 4*H gates
constexpr int NOPS   = 64;
constexpr int NEDGE  = 128;
constexpr float TEMP   = 5.0f;
constexpr float TCONST = 2.5f;
constexpr float TINY   = 1.1754943508222875e-38f;  // finfo(f32).tiny

__device__ __forceinline__ void tf_round(uint32_t& x0, uint32_t& x1, int r) {
  x0 += x1;
  x1 = (x1 << r) | (x1 >> (32 - r));
  x1 ^= x0;
}

// Threefry-2x32, 20 rounds — bit-exact JAX threefry2x32_p
__device__ __forceinline__ void tf2x32(uint32_t k0, uint32_t k1,
                                       uint32_t& x0, uint32_t& x1) {
  const uint32_t ks2 = k0 ^ k1 ^ 0x1BD11BDAu;
  x0 += k0; x1 += k1;
  tf_round(x0,x1,13); tf_round(x0,x1,15); tf_round(x0,x1,26); tf_round(x0,x1, 6);
  x0 += k1;  x1 += ks2 + 1u;
  tf_round(x0,x1,17); tf_round(x0,x1,29); tf_round(x0,x1,16); tf_round(x0,x1,24);
  x0 += ks2; x1 += k0 + 2u;
  tf_round(x0,x1,13); tf_round(x0,x1,15); tf_round(x0,x1,26); tf_round(x0,x1, 6);
  x0 += k0;  x1 += k1 + 3u;
  tf_round(x0,x1,17); tf_round(x0,x1,29); tf_round(x0,x1,16); tf_round(x0,x1,24);
  x0 += k1;  x1 += ks2 + 4u;
  tf_round(x0,x1,13); tf_round(x0,x1,15); tf_round(x0,x1,26); tf_round(x0,x1, 6);
  x0 += ks2; x1 += k0 + 5u;
}

__device__ __forceinline__ float sigmoidf_(float x) {
  return 1.0f / (1.0f + expf(-x));
}

__global__ __launch_bounds__(128, 1)
void ctrl_kernel(const float* __restrict__ input_vars,
                 const float* __restrict__ W_ih0, const float* __restrict__ W_hh0,
                 const float* __restrict__ b_ih0, const float* __restrict__ b_hh0,
                 const float* __restrict__ W_ih1, const float* __restrict__ W_hh1,
                 const float* __restrict__ b_ih1, const float* __restrict__ b_hh1,
                 const float* __restrict__ embd,
                 const float* __restrict__ W_pred, const float* __restrict__ b_pred,
                 float* __restrict__ out) {
  const int tid = threadIdx.x;  // 0..127, thread j owns gate row j

  __shared__ __align__(16) float xbuf[H];
  __shared__ __align__(16) float h0buf[H];
  __shared__ __align__(16) float h1buf[H];
  __shared__ __align__(16) float glds[G4];
  __shared__ __align__(16) float embd_lds[NOPS * H];

  // Register-resident weight rows (row j of each 128x32 matrix)
  float4 w_ih_0[8], w_hh_0[8], w_ih_1[8], w_hh_1[8], w_p[8];
#pragma unroll
  for (int q = 0; q < 8; ++q) {
    w_ih_0[q] = reinterpret_cast<const float4*>(W_ih0 + tid * H)[q];
    w_hh_0[q] = reinterpret_cast<const float4*>(W_hh0 + tid * H)[q];
    w_ih_1[q] = reinterpret_cast<const float4*>(W_ih1 + tid * H)[q];
    w_hh_1[q] = reinterpret_cast<const float4*>(W_hh1 + tid * H)[q];
  }
  const float bsum0 = b_ih0[tid] + b_hh0[tid];
  const float bsum1 = b_ih1[tid] + b_hh1[tid];
  float bp = 0.0f;
  if (tid < NOPS) {
#pragma unroll
    for (int q = 0; q < 8; ++q)
      w_p[q] = reinterpret_cast<const float4*>(W_pred + tid * H)[q];
    bp = b_pred[tid];
  } else {
#pragma unroll
    for (int q = 0; q < 8; ++q) w_p[q] = make_float4(0.f, 0.f, 0.f, 0.f);
  }

  for (int i = tid; i < NOPS * H; i += 128) embd_lds[i] = embd[i];
  if (tid < H) {
    xbuf[tid]  = input_vars[tid];
    h0buf[tid] = 0.0f;
    h1buf[tid] = 0.0f;
  }
  float c0 = 0.0f, c1 = 0.0f;     // cell state for lane tid<32
  uint32_t k0 = 0u, k1 = 42u;     // jax.random.key(42) -> (0, 42)
  float lp_sum = 0.0f, ent_sum = 0.0f;
  __syncthreads();

  for (int t = 0; t < NEDGE; ++t) {
    // ---- LSTM0 gate row tid: bsum0 + x.Wih0[tid] + h0.Whh0[tid] ----
    {
      const float4* xv = reinterpret_cast<const float4*>(xbuf);
      const float4* hv = reinterpret_cast<const float4*>(h0buf);
      float4 ax = make_float4(0.f,0.f,0.f,0.f), ah = make_float4(0.f,0.f,0.f,0.f);
#pragma unroll
      for (int q = 0; q < 8; ++q) {
        float4 xq = xv[q], hq = hv[q];
        ax.x += xq.x * w_ih_0[q].x; ax.y += xq.y * w_ih_0[q].y;
        ax.z += xq.z * w_ih_0[q].z; ax.w += xq.w * w_ih_0[q].w;
        ah.x += hq.x * w_hh_0[q].x; ah.y += hq.y * w_hh_0[q].y;
        ah.z += hq.z * w_hh_0[q].z; ah.w += hq.w * w_hh_0[q].w;
      }
      glds[tid] = bsum0 + ((ax.x + ax.y) + (ax.z + ax.w))
                        + ((ah.x + ah.y) + (ah.z + ah.w));
    }
    __syncthreads();
    if (tid < H) {  // gate order i,f,g,o
      float ig = glds[tid], fg = glds[H + tid];
      float gg = glds[2 * H + tid], og = glds[3 * H + tid];
      c0 = sigmoidf_(fg) * c0 + sigmoidf_(ig) * tanhf(gg);
      h0buf[tid] = sigmoidf_(og) * tanhf(c0);
    }
    __syncthreads();
    // ---- LSTM1 gate row tid (x := h0) ----
    {
      const float4* xv = reinterpret_cast<const float4*>(h0buf);
      const float4* hv = reinterpret_cast<const float4*>(h1buf);
      float4 ax = make_float4(0.f,0.f,0.f,0.f), ah = make_float4(0.f,0.f,0.f,0.f);
#pragma unroll
      for (int q = 0; q < 8; ++q) {
        float4 xq = xv[q], hq = hv[q];
        ax.x += xq.x * w_ih_1[q].x; ax.y += xq.y * w_ih_1[q].y;
        ax.z += xq.z * w_ih_1[q].z; ax.w += xq.w * w_ih_1[q].w;
        ah.x += hq.x * w_hh_1[q].x; ah.y += hq.y * w_hh_1[q].y;
        ah.z += hq.z * w_hh_1[q].z; ah.w += hq.w * w_hh_1[q].w;
      }
      glds[tid] = bsum1 + ((ax.x + ax.y) + (ax.z + ax.w))
                        + ((ah.x + ah.y) + (ah.z + ah.w));
    }
    __syncthreads();
    if (tid < H) {
      float ig = glds[tid], fg = glds[H + tid];
      float gg = glds[2 * H + tid], og = glds[3 * H + tid];
      c1 = sigmoidf_(fg) * c1 + sigmoidf_(ig) * tanhf(gg);
      h1buf[tid] = sigmoidf_(og) * tanhf(c1);
    }
    __syncthreads();
    // ---- sampling: wave 0 only (lanes 0..63), barrier-free shfl reductions ----
    if (tid < NOPS) {
      const float4* hv = reinterpret_cast<const float4*>(h1buf);
      float4 a = make_float4(0.f,0.f,0.f,0.f);
#pragma unroll
      for (int q = 0; q < 8; ++q) {
        float4 hq = hv[q];
        a.x += hq.x * w_p[q].x; a.y += hq.y * w_p[q].y;
        a.z += hq.z * w_p[q].z; a.w += hq.w * w_p[q].w;
      }
      float pre   = bp + ((a.x + a.y) + (a.z + a.w));
      float logit = TCONST * tanhf(pre / TEMP);

      // key, sub = split(key); bits = random_bits(sub, 32, (64,))[lane]
      uint32_t bits;
#if TF_MODE == 0
      uint32_t n0 = 0u, n1 = 0u; tf2x32(k0, k1, n0, n1);   // counts (0,0) -> new key
      uint32_t s0 = 0u, s1 = 1u; tf2x32(k0, k1, s0, s1);   // counts (0,1) -> sub
      uint32_t x0 = 0u, x1 = (uint32_t)tid;                 // 64-bit iota: (0, lane)
      tf2x32(s0, s1, x0, x1);
      bits = x0 ^ x1;                                       // fold to 32 bits
      k0 = n0; k1 = n1;
#else
      uint32_t a0 = 0u, a1 = 2u; tf2x32(k0, k1, a0, a1);   // pair (0,2)
      uint32_t b0 = 1u, b1 = 3u; tf2x32(k0, k1, b0, b1);   // pair (1,3)
      uint32_t s0 = a1, s1 = b1;                            // sub = (y1 of A, y1 of B)
      uint32_t p0 = (uint32_t)(tid & 31), p1 = (uint32_t)((tid & 31) + 32);
      tf2x32(s0, s1, p0, p1);
      bits = (tid < 32) ? p0 : p1;
      k0 = a0; k1 = b0;                                     // key = (y0 of A, y0 of B)
#endif
      // JAX uniform(minval=tiny, maxval=1) -> gumbel
      float u = __uint_as_float(0x3f800000u | (bits >> 9)) - 1.0f;
      u = fmaxf(u + TINY, TINY);
      float gum  = -logf(-logf(u));
      float pert = logit + gum;

      // argmax(pert), first index on ties
      float bv = pert; int bi = tid;
#pragma unroll
      for (int d = 32; d >= 1; d >>= 1) {
        float ov = __shfl_xor(bv, d, 64);
        int   oi = __shfl_xor(bi, d, 64);
        if (ov > bv || (ov == bv && oi < bi)) { bv = ov; bi = oi; }
      }
      const int idx = bi;

      // log_softmax stats: m, E = sum e^(s), ES = sum e^(s)*s
      float m = logit;
#pragma unroll
      for (int d = 32; d >= 1; d >>= 1) m = fmaxf(m, __shfl_xor(m, d, 64));
      float s = logit - m;
      float e = expf(s);
      float E = e, ES = e * s;
#pragma unroll
      for (int d = 32; d >= 1; d >>= 1) {
        E  += __shfl_xor(E, d, 64);
        ES += __shfl_xor(ES, d, 64);
      }
      float lse   = logf(E);
      float s_idx = __shfl(s, idx, 64);
      lp_sum  += s_idx - lse;       // logp[idx]
      ent_sum += lse - ES / E;      // -sum p*logp

      if (tid == 0) out[2 + t] = (float)idx;
      if (tid < H) xbuf[tid] = embd_lds[idx * H + tid];  // x = embd[idx]
    }
    __syncthreads();
  }

  if (tid == 0) { out[0] = lp_sum; out[1] = ent_sum; }
}

}  // namespace

extern "C" void kernel_launch(void* const* d_in, const int* in_sizes, int n_in,
                              void* d_out, int out_size, void* d_ws, size_t ws_size,
                              hipStream_t stream) {
  (void)in_sizes; (void)n_in; (void)d_ws; (void)ws_size; (void)out_size;
  const float* input_vars = (const float*)d_in[0];
  const float* W_ih0 = (const float*)d_in[1];
  const float* W_hh0 = (const float*)d_in[2];
  const float* b_ih0 = (const float*)d_in[3];
  const float* b_hh0 = (const float*)d_in[4];
  const float* W_ih1 = (const float*)d_in[5];
  const float* W_hh1 = (const float*)d_in[6];
  const float* b_ih1 = (const float*)d_in[7];
  const float* b_hh1 = (const float*)d_in[8];
  const float* embd  = (const float*)d_in[9];
  const float* W_pred = (const float*)d_in[10];
  const float* b_pred = (const float*)d_in[11];
  float* out = (float*)d_out;

  hipLaunchKernelGGL(ctrl_kernel, dim3(1), dim3(128), 0, stream,
                     input_vars, W_ih0, W_hh0, b_ih0, b_hh0,
                     W_ih1, W_hh1, b_ih1, b_hh1,
                     embd, W_pred, b_pred, out);
}

// Round 3
// 361.376 us; speedup vs baseline: 1.0816x; 1.0816x over previous
//
#include <hip/hip_runtime.h>
#include <stdint.h>

namespace {

constexpr int H      = 32;    // LSTM_SIZE
constexpr int NOPS   = 64;
constexpr int NEDGE  = 128;
constexpr float TEMP   = 5.0f;
constexpr float TCONST = 2.5f;
constexpr float TINY   = 1.1754943508222875e-38f;  // finfo(f32).tiny

__device__ __forceinline__ void tf_round(uint32_t& x0, uint32_t& x1, int r) {
  x0 += x1;
  x1 = (x1 << r) | (x1 >> (32 - r));
  x1 ^= x0;
}

// Threefry-2x32, 20 rounds — bit-exact JAX threefry2x32_p
__device__ __forceinline__ void tf2x32(uint32_t k0, uint32_t k1,
                                       uint32_t& x0, uint32_t& x1) {
  const uint32_t ks2 = k0 ^ k1 ^ 0x1BD11BDAu;
  x0 += k0; x1 += k1;
  tf_round(x0,x1,13); tf_round(x0,x1,15); tf_round(x0,x1,26); tf_round(x0,x1, 6);
  x0 += k1;  x1 += ks2 + 1u;
  tf_round(x0,x1,17); tf_round(x0,x1,29); tf_round(x0,x1,16); tf_round(x0,x1,24);
  x0 += ks2; x1 += k0 + 2u;
  tf_round(x0,x1,13); tf_round(x0,x1,15); tf_round(x0,x1,26); tf_round(x0,x1, 6);
  x0 += k0;  x1 += k1 + 3u;
  tf_round(x0,x1,17); tf_round(x0,x1,29); tf_round(x0,x1,16); tf_round(x0,x1,24);
  x0 += k1;  x1 += ks2 + 4u;
  tf_round(x0,x1,13); tf_round(x0,x1,15); tf_round(x0,x1,26); tf_round(x0,x1, 6);
  x0 += ks2; x1 += k0 + 5u;
}

__device__ __forceinline__ float sigmoidf_(float x) {
  return 1.0f / (1.0f + expf(-x));
}

__device__ __forceinline__ float rdlane(float v, int i) {
  return __int_as_float(__builtin_amdgcn_readlane(__float_as_int(v), i));
}

__device__ __forceinline__ void load_row(const float* __restrict__ p, float* dst) {
#pragma unroll
  for (int q = 0; q < 8; ++q) {
    float4 v = reinterpret_cast<const float4*>(p)[q];
    dst[4*q+0] = v.x; dst[4*q+1] = v.y; dst[4*q+2] = v.z; dst[4*q+3] = v.w;
  }
}

// gate = sum_k x[k]*wx[k] + h[k]*wh[k], 4 independent accumulator chains
__device__ __forceinline__ float dot_xh(const float* __restrict__ x,
                                        const float* __restrict__ wx,
                                        const float* __restrict__ h,
                                        const float* __restrict__ wh) {
  float a0 = 0.f, a1 = 0.f, a2 = 0.f, a3 = 0.f;
#pragma unroll
  for (int k = 0; k < H; k += 4) {
    a0 = fmaf(x[k+0], wx[k+0], a0);
    a1 = fmaf(x[k+1], wx[k+1], a1);
    a2 = fmaf(x[k+2], wx[k+2], a2);
    a3 = fmaf(x[k+3], wx[k+3], a3);
    a0 = fmaf(h[k+0], wh[k+0], a0);
    a1 = fmaf(h[k+1], wh[k+1], a1);
    a2 = fmaf(h[k+2], wh[k+2], a2);
    a3 = fmaf(h[k+3], wh[k+3], a3);
  }
  return (a0 + a1) + (a2 + a3);
}

__global__ __launch_bounds__(64, 1)
void ctrl_kernel(const float* __restrict__ input_vars,
                 const float* __restrict__ W_ih0, const float* __restrict__ W_hh0,
                 const float* __restrict__ b_ih0, const float* __restrict__ b_hh0,
                 const float* __restrict__ W_ih1, const float* __restrict__ W_hh1,
                 const float* __restrict__ b_ih1, const float* __restrict__ b_hh1,
                 const float* __restrict__ embd,
                 const float* __restrict__ W_pred, const float* __restrict__ b_pred,
                 float* __restrict__ out) {
  const int lane = threadIdx.x;        // 0..63, single wave
  const int rA = lane, rB = lane + 64; // owned gate rows: i/f (rA), g/o (rB)
  const bool lo = (lane < H);          // lower half owns i,g; upper owns f,o

  __shared__ __align__(16) float embd_lds[NOPS * H];  // read-only after init

  // ---- register-resident weights: rows rA,rB of each LSTM matrix + pred row
  float wi0A[H], wi0B[H], wh0A[H], wh0B[H];
  float wi1A[H], wi1B[H], wh1A[H], wh1B[H];
  float wp[H];
  load_row(W_ih0 + rA * H, wi0A);  load_row(W_ih0 + rB * H, wi0B);
  load_row(W_hh0 + rA * H, wh0A);  load_row(W_hh0 + rB * H, wh0B);
  load_row(W_ih1 + rA * H, wi1A);  load_row(W_ih1 + rB * H, wi1B);
  load_row(W_hh1 + rA * H, wh1A);  load_row(W_hh1 + rB * H, wh1B);
  load_row(W_pred + lane * H, wp);                    // NOPS==64, every lane valid
  const float bsum0A = b_ih0[rA] + b_hh0[rA];
  const float bsum0B = b_ih0[rB] + b_hh0[rB];
  const float bsum1A = b_ih1[rA] + b_hh1[rA];
  const float bsum1B = b_ih1[rB] + b_hh1[rB];
  const float bp = b_pred[lane];

  for (int i = lane; i < NOPS * H; i += 64) embd_lds[i] = embd[i];
  __syncthreads();  // single wave: compiles to (near-)nothing; orders embd init

  float xr[H];
#pragma unroll
  for (int q = 0; q < 8; ++q) {
    float4 v = reinterpret_cast<const float4*>(input_vars)[q];
    xr[4*q+0] = v.x; xr[4*q+1] = v.y; xr[4*q+2] = v.z; xr[4*q+3] = v.w;
  }
  float h0s[H], h1s[H];
#pragma unroll
  for (int k = 0; k < H; ++k) { h0s[k] = 0.f; h1s[k] = 0.f; }

  float c0 = 0.f, c1 = 0.f;        // cell state for cell (lane&31), both halves
  uint32_t k0 = 0u, k1 = 42u;      // jax.random.key(42)
  float lp_sum = 0.f, ent_sum = 0.f;

  for (int t = 0; t < NEDGE; ++t) {
    // ---- threefry + gumbel FIRST: depends only on key chain, interleaves
    //      with LSTM FMAs below (uniform ciphers -> SALU, per-lane -> VALU)
    uint32_t n0 = 0u, n1 = 0u; tf2x32(k0, k1, n0, n1);   // counts (0,0) -> new key
    uint32_t s0 = 0u, s1 = 1u; tf2x32(k0, k1, s0, s1);   // counts (0,1) -> subkey
    uint32_t x0 = 0u, x1 = (uint32_t)lane;               // iota64: (0, lane)
    tf2x32(s0, s1, x0, x1);
    const uint32_t bits = x0 ^ x1;
    k0 = n0; k1 = n1;
    float u = __uint_as_float(0x3f800000u | (bits >> 9)) - 1.0f;
    u = fmaxf(u + TINY, TINY);
    const float gum = -logf(-logf(u));

    // ---- LSTM0: gate rows rA (i|f) and rB (g|o)
    float gA = bsum0A + dot_xh(xr, wi0A, h0s, wh0A);
    float gB = bsum0B + dot_xh(xr, wi0B, h0s, wh0B);
    {
      float oA = __shfl_xor(gA, 32, 64);   // lo: f,  hi: i
      float oB = __shfl_xor(gB, 32, 64);   // lo: o,  hi: g
      float ig = lo ? gA : oA;
      float fg = lo ? oA : gA;
      float gg = lo ? gB : oB;
      float og = lo ? oB : gB;
      c0 = sigmoidf_(fg) * c0 + sigmoidf_(ig) * tanhf(gg);
      float h0v = sigmoidf_(og) * tanhf(c0);   // h0[lane&31] in every lane
#pragma unroll
      for (int i = 0; i < H; ++i) h0s[i] = rdlane(h0v, i);
    }

    // ---- LSTM1
    float gA1 = bsum1A + dot_xh(h0s, wi1A, h1s, wh1A);
    float gB1 = bsum1B + dot_xh(h0s, wi1B, h1s, wh1B);
    {
      float oA = __shfl_xor(gA1, 32, 64);
      float oB = __shfl_xor(gB1, 32, 64);
      float ig = lo ? gA1 : oA;
      float fg = lo ? oA : gA1;
      float gg = lo ? gB1 : oB;
      float og = lo ? oB : gB1;
      c1 = sigmoidf_(fg) * c1 + sigmoidf_(ig) * tanhf(gg);
      float h1v = sigmoidf_(og) * tanhf(c1);
#pragma unroll
      for (int i = 0; i < H; ++i) h1s[i] = rdlane(h1v, i);
    }

    // ---- logits + categorical sample (lane = op index)
    float p0 = 0.f, p1 = 0.f, p2 = 0.f, p3 = 0.f;
#pragma unroll
    for (int k = 0; k < H; k += 4) {
      p0 = fmaf(h1s[k+0], wp[k+0], p0);
      p1 = fmaf(h1s[k+1], wp[k+1], p1);
      p2 = fmaf(h1s[k+2], wp[k+2], p2);
      p3 = fmaf(h1s[k+3], wp[k+3], p3);
    }
    const float pre   = bp + ((p0 + p1) + (p2 + p3));
    const float logit = TCONST * tanhf(pre / TEMP);
    const float pert  = logit + gum;

    // argmax(pert), first index on ties
    float bv = pert; int bi = lane;
#pragma unroll
    for (int d = 32; d >= 1; d >>= 1) {
      float ov = __shfl_xor(bv, d, 64);
      int   oi = __shfl_xor(bi, d, 64);
      if (ov > bv || (ov == bv && oi < bi)) { bv = ov; bi = oi; }
    }
    const int idxu = __builtin_amdgcn_readfirstlane(bi);

    // x = embd[idx] — issue LDS broadcast reads now, consumed next iteration;
    // latency hides under the E/ES reduction below
#pragma unroll
    for (int q = 0; q < 8; ++q) {
      float4 v = reinterpret_cast<const float4*>(embd_lds + idxu * H)[q];
      xr[4*q+0] = v.x; xr[4*q+1] = v.y; xr[4*q+2] = v.z; xr[4*q+3] = v.w;
    }

    // log-softmax stats WITHOUT max-shift: logit in [-2.5,2.5] -> exp safe
    const float e = expf(logit);
    float E = e, ES = e * logit;
#pragma unroll
    for (int d = 32; d >= 1; d >>= 1) {
      E  += __shfl_xor(E, d, 64);
      ES += __shfl_xor(ES, d, 64);
    }
    const float lse = logf(E);
    const float li  = rdlane(logit, idxu);
    lp_sum  += li - lse;          // logp[idx]
    ent_sum += lse - ES / E;      // -sum p*logp

    if (lane == 0) out[2 + t] = (float)idxu;
  }

  if (lane == 0) { out[0] = lp_sum; out[1] = ent_sum; }
}

}  // namespace

extern "C" void kernel_launch(void* const* d_in, const int* in_sizes, int n_in,
                              void* d_out, int out_size, void* d_ws, size_t ws_size,
                              hipStream_t stream) {
  (void)in_sizes; (void)n_in; (void)d_ws; (void)ws_size; (void)out_size;
  const float* input_vars = (const float*)d_in[0];
  const float* W_ih0 = (const float*)d_in[1];
  const float* W_hh0 = (const float*)d_in[2];
  const float* b_ih0 = (const float*)d_in[3];
  const float* b_hh0 = (const float*)d_in[4];
  const float* W_ih1 = (const float*)d_in[5];
  const float* W_hh1 = (const float*)d_in[6];
  const float* b_ih1 = (const float*)d_in[7];
  const float* b_hh1 = (const float*)d_in[8];
  const float* embd  = (const float*)d_in[9];
  const float* W_pred = (const float*)d_in[10];
  const float* b_pred = (const float*)d_in[11];
  float* out = (float*)d_out;

  hipLaunchKernelGGL(ctrl_kernel, dim3(1), dim3(64), 0, stream,
                     input_vars, W_ih0, W_hh0, b_ih0, b_hh0,
                     W_ih1, W_hh1, b_ih1, b_hh1,
                     embd, W_pred, b_pred, out);
}

// Round 6
// 312.478 us; speedup vs baseline: 1.2508x; 1.1565x over previous
//
#include <hip/hip_runtime.h>
#include <stdint.h>

namespace {

constexpr int H      = 32;    // LSTM_SIZE
constexpr int NEDGE  = 128;
constexpr float TEMP   = 5.0f;
constexpr float TCONST = 2.5f;
constexpr float TINY   = 1.1754943508222875e-38f;  // finfo(f32).tiny

__device__ __forceinline__ void tf_round(uint32_t& x0, uint32_t& x1, int r) {
  x0 += x1;
  x1 = (x1 << r) | (x1 >> (32 - r));
  x1 ^= x0;
}

// Threefry-2x32, 20 rounds — bit-exact JAX threefry2x32_p
__device__ __forceinline__ void tf2x32(uint32_t k0, uint32_t k1,
                                       uint32_t& x0, uint32_t& x1) {
  const uint32_t ks2 = k0 ^ k1 ^ 0x1BD11BDAu;
  x0 += k0; x1 += k1;
  tf_round(x0,x1,13); tf_round(x0,x1,15); tf_round(x0,x1,26); tf_round(x0,x1, 6);
  x0 += k1;  x1 += ks2 + 1u;
  tf_round(x0,x1,17); tf_round(x0,x1,29); tf_round(x0,x1,16); tf_round(x0,x1,24);
  x0 += ks2; x1 += k0 + 2u;
  tf_round(x0,x1,13); tf_round(x0,x1,15); tf_round(x0,x1,26); tf_round(x0,x1, 6);
  x0 += k0;  x1 += k1 + 3u;
  tf_round(x0,x1,17); tf_round(x0,x1,29); tf_round(x0,x1,16); tf_round(x0,x1,24);
  x0 += k1;  x1 += ks2 + 4u;
  tf_round(x0,x1,13); tf_round(x0,x1,15); tf_round(x0,x1,26); tf_round(x0,x1, 6);
  x0 += ks2; x1 += k0 + 5u;
}

__device__ __forceinline__ float sigmoidf_(float x) {
  return 1.0f / (1.0f + expf(-x));
}

__device__ __forceinline__ float rdlane(float v, int i) {
  return __int_as_float(__builtin_amdgcn_readlane(__float_as_int(v), i));
}

template <int CTRL>
__device__ __forceinline__ float dppf(float v) {
  return __int_as_float(__builtin_amdgcn_update_dpp(
      __float_as_int(v), __float_as_int(v), CTRL, 0xF, 0xF, false));
}

// sum over 64 lanes -> uniform value (DPP butterfly within rows of 16,
// then 4 readlanes).  0xB1=quad_perm(1,0,3,2)  0x4E=quad_perm(2,3,0,1)
// 0x141=row_half_mirror  0x140=row_mirror
__device__ __forceinline__ float wave_sum64(float v) {
  v += dppf<0xB1>(v);
  v += dppf<0x4E>(v);
  v += dppf<0x141>(v);
  v += dppf<0x140>(v);
  return (rdlane(v, 15) + rdlane(v, 31)) + (rdlane(v, 47) + rdlane(v, 63));
}

__device__ __forceinline__ float wave_max64(float v) {
  v = fmaxf(v, dppf<0xB1>(v));
  v = fmaxf(v, dppf<0x4E>(v));
  v = fmaxf(v, dppf<0x141>(v));
  v = fmaxf(v, dppf<0x140>(v));
  return fmaxf(fmaxf(rdlane(v, 15), rdlane(v, 31)),
               fmaxf(rdlane(v, 47), rdlane(v, 63)));
}

__global__ __launch_bounds__(64, 1)
void ctrl_kernel(const float* __restrict__ input_vars,
                 const float* __restrict__ W_ih0, const float* __restrict__ W_hh0,
                 const float* __restrict__ b_ih0, const float* __restrict__ b_hh0,
                 const float* __restrict__ W_ih1, const float* __restrict__ W_hh1,
                 const float* __restrict__ b_ih1, const float* __restrict__ b_hh1,
                 const float* __restrict__ embd,
                 const float* __restrict__ W_pred, const float* __restrict__ b_pred,
                 float* __restrict__ out) {
  const int lane = threadIdx.x;        // 0..63, single wave, no barriers in loop
  const int rB   = lane + 64;          // second owned gate row
  const bool lo  = (lane < H);

  // [mat][k4][gate_row] float4 -> lane-linear ds_read_b128, conflict-free;
  // mat: 0=W_ih0 1=W_hh0 2=W_ih1 3=W_hh1.  Exactly 64 KiB.
  __shared__ float4 Wl[4][8][128];

#define STAGE(MAT, SRC)                                                    \
  _Pragma("unroll")                                                        \
  for (int j = 0; j < 16; ++j) {                                           \
    const int i = lane + 64 * j;                                           \
    const int k4 = i & 7, row = i >> 3;                                    \
    Wl[MAT][k4][row] = reinterpret_cast<const float4*>(SRC)[row * 8 + k4]; \
  }
  STAGE(0, W_ih0)
  STAGE(1, W_hh0)
  STAGE(2, W_ih1)
  STAGE(3, W_hh1)
#undef STAGE

  const float bsum0A = b_ih0[lane] + b_hh0[lane];
  const float bsum0B = b_ih0[rB]   + b_hh0[rB];
  const float bsum1A = b_ih1[lane] + b_hh1[lane];
  const float bsum1B = b_ih1[rB]   + b_hh1[rB];
  const float bp = b_pred[lane];
  float4 wp4[8];
#pragma unroll
  for (int q = 0; q < 8; ++q)
    wp4[q] = reinterpret_cast<const float4*>(W_pred + lane * H)[q];

  const float4* xsrc = reinterpret_cast<const float4*>(input_vars);  // uniform
  float h0v = 0.f, h1v = 0.f, c0 = 0.f, c1 = 0.f;
  uint32_t k0 = 0u, k1 = 42u;          // jax.random.key(42)
  float lp_sum = 0.f, ent_sum = 0.f;
  __syncthreads();                      // order LDS staging (single wave)

  for (int t = 0; t < NEDGE; ++t) {
    // ---- threefry + gumbel: only depends on key chain; interleaves with FMAs
    uint32_t n0 = 0u, n1 = 0u; tf2x32(k0, k1, n0, n1);
    uint32_t s0 = 0u, s1 = 1u; tf2x32(k0, k1, s0, s1);
    uint32_t x0 = 0u, x1 = (uint32_t)lane;
    tf2x32(s0, s1, x0, x1);
    const uint32_t bits = x0 ^ x1;
    k0 = n0; k1 = n1;
    float u = __uint_as_float(0x3f800000u | (bits >> 9)) - 1.0f;
    u = fmaxf(u + TINY, TINY);
    const float gum = -logf(-logf(u));

    // ---- LSTM0: rows lane (i|f) and lane+64 (g|o); x via uniform loads,
    //      h via readlane->SGPR.  Accumulation order identical to R3 (passed).
    float aA0=0.f,aA1=0.f,aA2=0.f,aA3=0.f, aB0=0.f,aB1=0.f,aB2=0.f,aB3=0.f;
#pragma unroll
    for (int q = 0; q < 8; ++q) {
      const float4 xq  = xsrc[q];            // uniform address -> broadcast
      const float4 wiA = Wl[0][q][lane];
      const float4 wiB = Wl[0][q][rB];
      const float4 whA = Wl[1][q][lane];
      const float4 whB = Wl[1][q][rB];
      const float h0 = rdlane(h0v, 4*q+0), h1 = rdlane(h0v, 4*q+1);
      const float h2 = rdlane(h0v, 4*q+2), h3 = rdlane(h0v, 4*q+3);
      aA0 = fmaf(xq.x, wiA.x, aA0); aA0 = fmaf(h0, whA.x, aA0);
      aA1 = fmaf(xq.y, wiA.y, aA1); aA1 = fmaf(h1, whA.y, aA1);
      aA2 = fmaf(xq.z, wiA.z, aA2); aA2 = fmaf(h2, whA.z, aA2);
      aA3 = fmaf(xq.w, wiA.w, aA3); aA3 = fmaf(h3, whA.w, aA3);
      aB0 = fmaf(xq.x, wiB.x, aB0); aB0 = fmaf(h0, whB.x, aB0);
      aB1 = fmaf(xq.y, wiB.y, aB1); aB1 = fmaf(h1, whB.y, aB1);
      aB2 = fmaf(xq.z, wiB.z, aB2); aB2 = fmaf(h2, whB.z, aB2);
      aB3 = fmaf(xq.w, wiB.w, aB3); aB3 = fmaf(h3, whB.w, aB3);
    }
    {
      const float gA = bsum0A + ((aA0 + aA1) + (aA2 + aA3));
      const float gB = bsum0B + ((aB0 + aB1) + (aB2 + aB3));
      const float oA = __shfl_xor(gA, 32, 64);
      const float oB = __shfl_xor(gB, 32, 64);
      const float ig = lo ? gA : oA, fg = lo ? oA : gA;
      const float gg = lo ? gB : oB, og = lo ? oB : gB;
      c0 = sigmoidf_(fg) * c0 + sigmoidf_(ig) * tanhf(gg);
      h0v = sigmoidf_(og) * tanhf(c0);       // h0[lane&31] in every lane
    }

    // ---- LSTM1: input h0v, state h1v (both via readlane)
    float bA0=0.f,bA1=0.f,bA2=0.f,bA3=0.f, bB0=0.f,bB1=0.f,bB2=0.f,bB3=0.f;
#pragma unroll
    for (int q = 0; q < 8; ++q) {
      const float4 wiA = Wl[2][q][lane];
      const float4 wiB = Wl[2][q][rB];
      const float4 whA = Wl[3][q][lane];
      const float4 whB = Wl[3][q][rB];
      const float x0s = rdlane(h0v, 4*q+0), x1s = rdlane(h0v, 4*q+1);
      const float x2s = rdlane(h0v, 4*q+2), x3s = rdlane(h0v, 4*q+3);
      const float y0s = rdlane(h1v, 4*q+0), y1s = rdlane(h1v, 4*q+1);
      const float y2s = rdlane(h1v, 4*q+2), y3s = rdlane(h1v, 4*q+3);
      bA0 = fmaf(x0s, wiA.x, bA0); bA0 = fmaf(y0s, whA.x, bA0);
      bA1 = fmaf(x1s, wiA.y, bA1); bA1 = fmaf(y1s, whA.y, bA1);
      bA2 = fmaf(x2s, wiA.z, bA2); bA2 = fmaf(y2s, whA.z, bA2);
      bA3 = fmaf(x3s, wiA.w, bA3); bA3 = fmaf(y3s, whA.w, bA3);
      bB0 = fmaf(x0s, wiB.x, bB0); bB0 = fmaf(y0s, whB.x, bB0);
      bB1 = fmaf(x1s, wiB.y, bB1); bB1 = fmaf(y1s, whB.y, bB1);
      bB2 = fmaf(x2s, wiB.z, bB2); bB2 = fmaf(y2s, whB.z, bB2);
      bB3 = fmaf(x3s, wiB.w, bB3); bB3 = fmaf(y3s, whB.w, bB3);
    }
    {
      const float gA = bsum1A + ((bA0 + bA1) + (bA2 + bA3));
      const float gB = bsum1B + ((bB0 + bB1) + (bB2 + bB3));
      const float oA = __shfl_xor(gA, 32, 64);
      const float oB = __shfl_xor(gB, 32, 64);
      const float ig = lo ? gA : oA, fg = lo ? oA : gA;
      const float gg = lo ? gB : oB, og = lo ? oB : gB;
      c1 = sigmoidf_(fg) * c1 + sigmoidf_(ig) * tanhf(gg);
      h1v = sigmoidf_(og) * tanhf(c1);
    }

    // ---- logits (lane = op index), W_pred register-resident
    float p0 = 0.f, p1 = 0.f, p2 = 0.f, p3 = 0.f;
#pragma unroll
    for (int q = 0; q < 8; ++q) {
      const float t0 = rdlane(h1v, 4*q+0), t1 = rdlane(h1v, 4*q+1);
      const float t2 = rdlane(h1v, 4*q+2), t3 = rdlane(h1v, 4*q+3);
      p0 = fmaf(t0, wp4[q].x, p0);
      p1 = fmaf(t1, wp4[q].y, p1);
      p2 = fmaf(t2, wp4[q].z, p2);
      p3 = fmaf(t3, wp4[q].w, p3);
    }
    const float pre   = bp + ((p0 + p1) + (p2 + p3));
    const float logit = TCONST * tanhf(pre / TEMP);
    const float pert  = logit + gum;

    // ---- categorical: argmax via DPP-max + ballot (tie -> lowest index)
    const float M = wave_max64(pert);
    const unsigned long long msk = __ballot(pert == M);
    const int idxu = __ffsll((long long)msk) - 1;   // uniform (SGPR)

    xsrc = reinterpret_cast<const float4*>(embd) + idxu * 8;  // next-step x

    // ---- log-softmax stats, no max-shift (logit in [-2.5,2.5])
    const float e  = expf(logit);
    const float E  = wave_sum64(e);
    const float ES = wave_sum64(e * logit);
    const float lse = logf(E);
    const float li  = rdlane(logit, idxu);
    lp_sum  += li - lse;
    ent_sum += lse - ES / E;

    if (lane == 0) out[2 + t] = (float)idxu;
  }

  if (lane == 0) { out[0] = lp_sum; out[1] = ent_sum; }
}

}  // namespace

extern "C" void kernel_launch(void* const* d_in, const int* in_sizes, int n_in,
                              void* d_out, int out_size, void* d_ws, size_t ws_size,
                              hipStream_t stream) {
  (void)in_sizes; (void)n_in; (void)d_ws; (void)ws_size; (void)out_size;
  const float* input_vars = (const float*)d_in[0];
  const float* W_ih0 = (const float*)d_in[1];
  const float* W_hh0 = (const float*)d_in[2];
  const float* b_ih0 = (const float*)d_in[3];
  const float* b_hh0 = (const float*)d_in[4];
  const float* W_ih1 = (const float*)d_in[5];
  const float* W_hh1 = (const float*)d_in[6];
  const float* b_ih1 = (const float*)d_in[7];
  const float* b_hh1 = (const float*)d_in[8];
  const float* embd  = (const float*)d_in[9];
  const float* W_pred = (const float*)d_in[10];
  const float* b_pred = (const float*)d_in[11];
  float* out = (float*)d_out;

  hipLaunchKernelGGL(ctrl_kernel, dim3(1), dim3(64), 0, stream,
                     input_vars, W_ih0, W_hh0, b_ih0, b_hh0,
                     W_ih1, W_hh1, b_ih1, b_hh1,
                     embd, W_pred, b_pred, out);
}

// Round 8
// 291.118 us; speedup vs baseline: 1.3426x; 1.0734x over previous
//
#include <hip/hip_runtime.h>
#include <stdint.h>

namespace {

typedef float v2f __attribute__((ext_vector_type(2)));

constexpr int H      = 32;    // LSTM_SIZE
constexpr int NEDGE  = 128;
constexpr float TEMP   = 5.0f;
constexpr float TCONST = 2.5f;
constexpr float TINY   = 1.1754943508222875e-38f;  // finfo(f32).tiny

__device__ __forceinline__ void tf_round(uint32_t& x0, uint32_t& x1, int r) {
  x0 += x1;
  x1 = (x1 << r) | (x1 >> (32 - r));
  x1 ^= x0;
}

// Threefry-2x32, 20 rounds — bit-exact JAX threefry2x32_p
__device__ __forceinline__ void tf2x32(uint32_t k0, uint32_t k1,
                                       uint32_t& x0, uint32_t& x1) {
  const uint32_t ks2 = k0 ^ k1 ^ 0x1BD11BDAu;
  x0 += k0; x1 += k1;
  tf_round(x0,x1,13); tf_round(x0,x1,15); tf_round(x0,x1,26); tf_round(x0,x1, 6);
  x0 += k1;  x1 += ks2 + 1u;
  tf_round(x0,x1,17); tf_round(x0,x1,29); tf_round(x0,x1,16); tf_round(x0,x1,24);
  x0 += ks2; x1 += k0 + 2u;
  tf_round(x0,x1,13); tf_round(x0,x1,15); tf_round(x0,x1,26); tf_round(x0,x1, 6);
  x0 += k0;  x1 += k1 + 3u;
  tf_round(x0,x1,17); tf_round(x0,x1,29); tf_round(x0,x1,16); tf_round(x0,x1,24);
  x0 += k1;  x1 += ks2 + 4u;
  tf_round(x0,x1,13); tf_round(x0,x1,15); tf_round(x0,x1,26); tf_round(x0,x1, 6);
  x0 += ks2; x1 += k0 + 5u;
}

__device__ __forceinline__ float sigmoidf_(float x) {
  return 1.0f / (1.0f + expf(-x));
}

__device__ __forceinline__ float rdlane(float v, int i) {
  return __int_as_float(__builtin_amdgcn_readlane(__float_as_int(v), i));
}

template <int CTRL>
__device__ __forceinline__ float dppf(float v) {
  return __int_as_float(__builtin_amdgcn_update_dpp(
      __float_as_int(v), __float_as_int(v), CTRL, 0xF, 0xF, false));
}

// 64-lane reductions: DPP butterfly within rows of 16, then 4 readlanes.
__device__ __forceinline__ float wave_sum64(float v) {
  v += dppf<0xB1>(v);
  v += dppf<0x4E>(v);
  v += dppf<0x141>(v);
  v += dppf<0x140>(v);
  return (rdlane(v, 15) + rdlane(v, 31)) + (rdlane(v, 47) + rdlane(v, 63));
}

__device__ __forceinline__ float wave_max64(float v) {
  v = fmaxf(v, dppf<0xB1>(v));
  v = fmaxf(v, dppf<0x4E>(v));
  v = fmaxf(v, dppf<0x141>(v));
  v = fmaxf(v, dppf<0x140>(v));
  return fmaxf(fmaxf(rdlane(v, 15), rdlane(v, 31)),
               fmaxf(rdlane(v, 47), rdlane(v, 63)));
}

__device__ __forceinline__ v2f pkfma(v2f a, v2f b, v2f c) {
  return __builtin_elementwise_fma(a, b, c);   // -> v_pk_fma_f32
}

__global__ __launch_bounds__(64, 1)
void ctrl_kernel(const float* __restrict__ input_vars,
                 const float* __restrict__ W_ih0, const float* __restrict__ W_hh0,
                 const float* __restrict__ b_ih0, const float* __restrict__ b_hh0,
                 const float* __restrict__ W_ih1, const float* __restrict__ W_hh1,
                 const float* __restrict__ b_ih1, const float* __restrict__ b_hh1,
                 const float* __restrict__ embd,
                 const float* __restrict__ W_pred, const float* __restrict__ b_pred,
                 float* __restrict__ out) {
  const int lane = threadIdx.x;        // 0..63, single wave, no barriers in loop
  const int rB   = lane + 64;          // second owned gate row
  const bool lo  = (lane < H);

  // [mat][k4][gate_row] float4 -> lane-linear ds_read_b128, conflict-free;
  // mat: 0=W_ih0 1=W_hh0 2=W_ih1 3=W_hh1.  64 KiB.
  __shared__ float4 Wl[4][8][128];
  __shared__ __align__(16) float hb0[H];      // h0 broadcast buffer
  __shared__ __align__(16) float hb1[H];      // h1 broadcast buffer
  __shared__ __align__(16) float arch_lds[NEDGE];  // sampled indices

#define STAGE(MAT, SRC)                                                    \
  _Pragma("unroll")                                                        \
  for (int j = 0; j < 16; ++j) {                                           \
    const int i = lane + 64 * j;                                           \
    const int k4 = i & 7, row = i >> 3;                                    \
    Wl[MAT][k4][row] = reinterpret_cast<const float4*>(SRC)[row * 8 + k4]; \
  }
  STAGE(0, W_ih0)
  STAGE(1, W_hh0)
  STAGE(2, W_ih1)
  STAGE(3, W_hh1)
#undef STAGE
  hb0[lane & 31] = 0.f;                 // 2 lanes/addr, same data: free
  hb1[lane & 31] = 0.f;

  const float bsum0A = b_ih0[lane] + b_hh0[lane];
  const float bsum0B = b_ih0[rB]   + b_hh0[rB];
  const float bsum1A = b_ih1[lane] + b_hh1[lane];
  const float bsum1B = b_ih1[rB]   + b_hh1[rB];
  const float bp = b_pred[lane];
  v2f wp01[8], wp23[8];
#pragma unroll
  for (int q = 0; q < 8; ++q) {
    const float4 w = reinterpret_cast<const float4*>(W_pred + lane * H)[q];
    wp01[q] = v2f{w.x, w.y};
    wp23[q] = v2f{w.z, w.w};
  }

  float4 xq[8];                         // current-step input row (registers)
#pragma unroll
  for (int q = 0; q < 8; ++q)
    xq[q] = reinterpret_cast<const float4*>(input_vars)[q];

  float c0 = 0.f, c1 = 0.f;
  uint32_t k0 = 0u, k1 = 42u;          // jax.random.key(42)
  float lp_sum = 0.f, ent_sum = 0.f;
  __syncthreads();                      // order LDS staging (single wave)

  for (int t = 0; t < NEDGE; ++t) {
    // ---- threefry folded: one per-lane cipher computes BOTH split outputs
    //      (lane0 -> new key, lane1 -> subkey), then per-lane bits cipher.
    uint32_t r0 = 0u, r1 = (uint32_t)(lane & 1);
    tf2x32(k0, k1, r0, r1);
    const uint32_t n0 = (uint32_t)__builtin_amdgcn_readlane((int)r0, 0);
    const uint32_t n1 = (uint32_t)__builtin_amdgcn_readlane((int)r1, 0);
    const uint32_t s0 = (uint32_t)__builtin_amdgcn_readlane((int)r0, 1);
    const uint32_t s1 = (uint32_t)__builtin_amdgcn_readlane((int)r1, 1);
    uint32_t x0 = 0u, x1 = (uint32_t)lane;
    tf2x32(s0, s1, x0, x1);
    const uint32_t bits = x0 ^ x1;
    k0 = n0; k1 = n1;
    float u = __uint_as_float(0x3f800000u | (bits >> 9)) - 1.0f;
    u = fmaxf(u + TINY, TINY);
    const float gum = -logf(-logf(u));

    // ---- LSTM0: rows lane (i|f), lane+64 (g|o); x in regs, h0 via LDS bcast
    {
      v2f aA01 = {0.f, 0.f}, aA23 = {0.f, 0.f};
      v2f aB01 = {0.f, 0.f}, aB23 = {0.f, 0.f};
#pragma unroll
      for (int q = 0; q < 8; ++q) {
        const float4 wiA = Wl[0][q][lane];
        const float4 wiB = Wl[0][q][rB];
        const float4 whA = Wl[1][q][lane];
        const float4 whB = Wl[1][q][rB];
        const float4 x4  = xq[q];
        const float4 h4  = *reinterpret_cast<const float4*>(&hb0[4 * q]);
        const v2f xlo = {x4.x, x4.y}, xhi = {x4.z, x4.w};
        const v2f hlo = {h4.x, h4.y}, hhi = {h4.z, h4.w};
        aA01 = pkfma(xlo, v2f{wiA.x, wiA.y}, aA01);
        aA01 = pkfma(hlo, v2f{whA.x, whA.y}, aA01);
        aA23 = pkfma(xhi, v2f{wiA.z, wiA.w}, aA23);
        aA23 = pkfma(hhi, v2f{whA.z, whA.w}, aA23);
        aB01 = pkfma(xlo, v2f{wiB.x, wiB.y}, aB01);
        aB01 = pkfma(hlo, v2f{whB.x, whB.y}, aB01);
        aB23 = pkfma(xhi, v2f{wiB.z, wiB.w}, aB23);
        aB23 = pkfma(hhi, v2f{whB.z, whB.w}, aB23);
      }
      const float gA = bsum0A + ((aA01.x + aA01.y) + (aA23.x + aA23.y));
      const float gB = bsum0B + ((aB01.x + aB01.y) + (aB23.x + aB23.y));
      const float oA = __shfl_xor(gA, 32, 64);
      const float oB = __shfl_xor(gB, 32, 64);
      const float ig = lo ? gA : oA, fg = lo ? oA : gA;
      const float gg = lo ? gB : oB, og = lo ? oB : gB;
      c0 = sigmoidf_(fg) * c0 + sigmoidf_(ig) * tanhf(gg);
      const float h0v = sigmoidf_(og) * tanhf(c0);
      hb0[lane & 31] = h0v;             // broadcast for LSTM1 + next step
    }

    // ---- LSTM1: input = fresh hb0, state = old hb1
    {
      v2f aA01 = {0.f, 0.f}, aA23 = {0.f, 0.f};
      v2f aB01 = {0.f, 0.f}, aB23 = {0.f, 0.f};
#pragma unroll
      for (int q = 0; q < 8; ++q) {
        const float4 wiA = Wl[2][q][lane];
        const float4 wiB = Wl[2][q][rB];
        const float4 whA = Wl[3][q][lane];
        const float4 whB = Wl[3][q][rB];
        const float4 x4  = *reinterpret_cast<const float4*>(&hb0[4 * q]);
        const float4 y4  = *reinterpret_cast<const float4*>(&hb1[4 * q]);
        const v2f xlo = {x4.x, x4.y}, xhi = {x4.z, x4.w};
        const v2f ylo = {y4.x, y4.y}, yhi = {y4.z, y4.w};
        aA01 = pkfma(xlo, v2f{wiA.x, wiA.y}, aA01);
        aA01 = pkfma(ylo, v2f{whA.x, whA.y}, aA01);
        aA23 = pkfma(xhi, v2f{wiA.z, wiA.w}, aA23);
        aA23 = pkfma(yhi, v2f{whA.z, whA.w}, aA23);
        aB01 = pkfma(xlo, v2f{wiB.x, wiB.y}, aB01);
        aB01 = pkfma(ylo, v2f{whB.x, whB.y}, aB01);
        aB23 = pkfma(xhi, v2f{wiB.z, wiB.w}, aB23);
        aB23 = pkfma(yhi, v2f{whB.z, whB.w}, aB23);
      }
      const float gA = bsum1A + ((aA01.x + aA01.y) + (aA23.x + aA23.y));
      const float gB = bsum1B + ((aB01.x + aB01.y) + (aB23.x + aB23.y));
      const float oA = __shfl_xor(gA, 32, 64);
      const float oB = __shfl_xor(gB, 32, 64);
      const float ig = lo ? gA : oA, fg = lo ? oA : gA;
      const float gg = lo ? gB : oB, og = lo ? oB : gB;
      c1 = sigmoidf_(fg) * c1 + sigmoidf_(ig) * tanhf(gg);
      const float h1v = sigmoidf_(og) * tanhf(c1);
      hb1[lane & 31] = h1v;
    }

    // ---- logits (lane = op index): h1 via LDS broadcast, W_pred in regs
    v2f p01 = {0.f, 0.f}, p23 = {0.f, 0.f};
#pragma unroll
    for (int q = 0; q < 8; ++q) {
      const float4 t4 = *reinterpret_cast<const float4*>(&hb1[4 * q]);
      p01 = pkfma(v2f{t4.x, t4.y}, wp01[q], p01);
      p23 = pkfma(v2f{t4.z, t4.w}, wp23[q], p23);
    }
    const float pre   = bp + ((p01.x + p01.y) + (p23.x + p23.y));
    const float logit = TCONST * tanhf(pre / TEMP);
    const float pert  = logit + gum;

    // ---- categorical: argmax via DPP-max + ballot (tie -> lowest index)
    const float M = wave_max64(pert);
    const unsigned long long msk = __ballot(pert == M);
    const int idxu = __ffsll((long long)msk) - 1;   // uniform

    // ---- prefetch next-step x = embd[idx] NOW; latency hides under softmax
    {
      const float4* xs = reinterpret_cast<const float4*>(embd) + (idxu << 3);
#pragma unroll
      for (int q = 0; q < 8; ++q) xq[q] = xs[q];
    }

    // ---- log-softmax stats, no max-shift (logit in [-2.5,2.5])
    const float e  = expf(logit);
    const float E  = wave_sum64(e);
    const float ES = wave_sum64(e * logit);
    const float lse = logf(E);
    const float li  = rdlane(logit, idxu);
    lp_sum  += li - lse;
    ent_sum += lse - ES / E;

    // ---- record sampled index: uniform addr+data LDS write (no branch)
    arch_lds[t] = (float)idxu;
  }

  // coalesced arch writeback
  out[2 + lane]      = arch_lds[lane];
  out[2 + 64 + lane] = arch_lds[64 + lane];
  if (lane == 0) { out[0] = lp_sum; out[1] = ent_sum; }
}

}  // namespace

extern "C" void kernel_launch(void* const* d_in, const int* in_sizes, int n_in,
                              void* d_out, int out_size, void* d_ws, size_t ws_size,
                              hipStream_t stream) {
  (void)in_sizes; (void)n_in; (void)d_ws; (void)ws_size; (void)out_size;
  const float* input_vars = (const float*)d_in[0];
  const float* W_ih0 = (const float*)d_in[1];
  const float* W_hh0 = (const float*)d_in[2];
  const float* b_ih0 = (const float*)d_in[3];
  const float* b_hh0 = (const float*)d_in[4];
  const float* W_ih1 = (const float*)d_in[5];
  const float* W_hh1 = (const float*)d_in[6];
  const float* b_ih1 = (const float*)d_in[7];
  const float* b_hh1 = (const float*)d_in[8];
  const float* embd  = (const float*)d_in[9];
  const float* W_pred = (const float*)d_in[10];
  const float* b_pred = (const float*)d_in[11];
  float* out = (float*)d_out;

  hipLaunchKernelGGL(ctrl_kernel, dim3(1), dim3(64), 0, stream,
                     input_vars, W_ih0, W_hh0, b_ih0, b_hh0,
                     W_ih1, W_hh1, b_ih1, b_hh1,
                     embd, W_pred, b_pred, out);
}

// Round 9
// 222.408 us; speedup vs baseline: 1.7574x; 1.3089x over previous
//
#include <hip/hip_runtime.h>
#include <stdint.h>

namespace {

typedef float v2f __attribute__((ext_vector_type(2)));

constexpr int H      = 32;    // LSTM_SIZE
constexpr int NEDGE  = 128;
constexpr float TINY   = 1.1754943508222875e-38f;  // finfo(f32).tiny
constexpr float L2E    = 1.4426950408889634f;      // log2(e)
constexpr float LN2    = 0.6931471805599453f;

__device__ __forceinline__ void tf_round(uint32_t& x0, uint32_t& x1, int r) {
  x0 += x1;
  x1 = (x1 << r) | (x1 >> (32 - r));
  x1 ^= x0;
}

// Threefry-2x32, 20 rounds — bit-exact JAX threefry2x32_p
__device__ __forceinline__ void tf2x32(uint32_t k0, uint32_t k1,
                                       uint32_t& x0, uint32_t& x1) {
  const uint32_t ks2 = k0 ^ k1 ^ 0x1BD11BDAu;
  x0 += k0; x1 += k1;
  tf_round(x0,x1,13); tf_round(x0,x1,15); tf_round(x0,x1,26); tf_round(x0,x1, 6);
  x0 += k1;  x1 += ks2 + 1u;
  tf_round(x0,x1,17); tf_round(x0,x1,29); tf_round(x0,x1,16); tf_round(x0,x1,24);
  x0 += ks2; x1 += k0 + 2u;
  tf_round(x0,x1,13); tf_round(x0,x1,15); tf_round(x0,x1,26); tf_round(x0,x1, 6);
  x0 += k0;  x1 += k1 + 3u;
  tf_round(x0,x1,17); tf_round(x0,x1,29); tf_round(x0,x1,16); tf_round(x0,x1,24);
  x0 += k1;  x1 += ks2 + 4u;
  tf_round(x0,x1,13); tf_round(x0,x1,15); tf_round(x0,x1,26); tf_round(x0,x1, 6);
  x0 += ks2; x1 += k0 + 5u;
}

// ---- native-instruction transcendentals (v_exp_f32 / v_log_f32 / v_rcp_f32)
__device__ __forceinline__ float fexp(float x) {       // e^x
  return __builtin_amdgcn_exp2f(x * L2E);
}
__device__ __forceinline__ float flog(float x) {       // ln(x)
  return __builtin_amdgcn_logf(x) * LN2;
}
__device__ __forceinline__ float fsigmoid(float x) {   // 1/(1+e^-x)
  return __builtin_amdgcn_rcpf(1.0f + __builtin_amdgcn_exp2f(-x * L2E));
}
__device__ __forceinline__ float ftanh(float x) {
  const float ax = __builtin_fabsf(x);
  const float t  = __builtin_amdgcn_exp2f(ax * (-2.0f * L2E));  // e^(-2|x|)
  const float r  = (1.0f - t) * __builtin_amdgcn_rcpf(1.0f + t);
  return __builtin_copysignf(r, x);
}

__device__ __forceinline__ float rdlane(float v, int i) {
  return __int_as_float(__builtin_amdgcn_readlane(__float_as_int(v), i));
}

template <int CTRL>
__device__ __forceinline__ float dppf(float v) {
  return __int_as_float(__builtin_amdgcn_update_dpp(
      __float_as_int(v), __float_as_int(v), CTRL, 0xF, 0xF, false));
}

// 64-lane reductions: DPP butterfly within rows of 16, then 4 readlanes.
__device__ __forceinline__ float wave_sum64(float v) {
  v += dppf<0xB1>(v);
  v += dppf<0x4E>(v);
  v += dppf<0x141>(v);
  v += dppf<0x140>(v);
  return (rdlane(v, 15) + rdlane(v, 31)) + (rdlane(v, 47) + rdlane(v, 63));
}

__device__ __forceinline__ float wave_max64(float v) {
  v = fmaxf(v, dppf<0xB1>(v));
  v = fmaxf(v, dppf<0x4E>(v));
  v = fmaxf(v, dppf<0x141>(v));
  v = fmaxf(v, dppf<0x140>(v));
  return fmaxf(fmaxf(rdlane(v, 15), rdlane(v, 31)),
               fmaxf(rdlane(v, 47), rdlane(v, 63)));
}

__device__ __forceinline__ v2f pkfma(v2f a, v2f b, v2f c) {
  return __builtin_elementwise_fma(a, b, c);   // -> v_pk_fma_f32
}

// 32-MAC dot of readlane-broadcast vector hsrc against LDS row, 4 chains.
#define H_DOT(ACC0, ACC1, ACC2, ACC3, HSRC, WMAT, ROW)                     \
  _Pragma("unroll")                                                        \
  for (int q = 0; q < 8; ++q) {                                            \
    const float4 w = WMAT[q][ROW];                                         \
    ACC0 = fmaf(rdlane(HSRC, 4*q+0), w.x, ACC0);                           \
    ACC1 = fmaf(rdlane(HSRC, 4*q+1), w.y, ACC1);                           \
    ACC2 = fmaf(rdlane(HSRC, 4*q+2), w.z, ACC2);                           \
    ACC3 = fmaf(rdlane(HSRC, 4*q+3), w.w, ACC3);                           \
  }

__global__ __launch_bounds__(64, 1)
void ctrl_kernel(const float* __restrict__ input_vars,
                 const float* __restrict__ W_ih0, const float* __restrict__ W_hh0,
                 const float* __restrict__ b_ih0, const float* __restrict__ b_hh0,
                 const float* __restrict__ W_ih1, const float* __restrict__ W_hh1,
                 const float* __restrict__ b_ih1, const float* __restrict__ b_hh1,
                 const float* __restrict__ embd,
                 const float* __restrict__ W_pred, const float* __restrict__ b_pred,
                 float* __restrict__ out) {
  const int lane = threadIdx.x;        // 0..63, single wave, no barriers in loop
  const int rB   = lane + 64;          // second owned gate row
  const bool lo  = (lane < H);

  // Weights [mat][k4][gate_row] float4, lane-linear ds_read_b128 (64 KiB);
  // embd table (8 KiB); arch indices (512 B).
  __shared__ float4 Wl[4][8][128];
  __shared__ __align__(16) float embd_lds[64 * H];
  __shared__ __align__(16) float arch_lds[NEDGE];

#define STAGE(MAT, SRC)                                                    \
  _Pragma("unroll")                                                        \
  for (int j = 0; j < 16; ++j) {                                           \
    const int i = lane + 64 * j;                                           \
    const int k4 = i & 7, row = i >> 3;                                    \
    Wl[MAT][k4][row] = reinterpret_cast<const float4*>(SRC)[row * 8 + k4]; \
  }
  STAGE(0, W_ih0)
  STAGE(1, W_hh0)
  STAGE(2, W_ih1)
  STAGE(3, W_hh1)
#undef STAGE
#pragma unroll
  for (int j = 0; j < 8; ++j)
    reinterpret_cast<float4*>(embd_lds)[lane + 64 * j] =
        reinterpret_cast<const float4*>(embd)[lane + 64 * j];

  const float bsum0A = b_ih0[lane] + b_hh0[lane];
  const float bsum0B = b_ih0[rB]   + b_hh0[rB];
  const float bsum1A = b_ih1[lane] + b_hh1[lane];
  const float bsum1B = b_ih1[rB]   + b_hh1[rB];
  const float bp = b_pred[lane];
  float4 wp4[8];
#pragma unroll
  for (int q = 0; q < 8; ++q)
    wp4[q] = reinterpret_cast<const float4*>(W_pred + lane * H)[q];

  float4 xq[8];                         // current-step input row (registers)
#pragma unroll
  for (int q = 0; q < 8; ++q)
    xq[q] = reinterpret_cast<const float4*>(input_vars)[q];

  float h0v = 0.f, h1v = 0.f, c0 = 0.f, c1 = 0.f;
  uint32_t k0 = 0u, k1 = 42u;          // jax.random.key(42)
  float lp_sum = 0.f, ent_sum = 0.f;
  __syncthreads();                      // order LDS staging (single wave)

#pragma unroll 2
  for (int t = 0; t < NEDGE; ++t) {
    // ---- threefry + gumbel (key chain only; overlaps everything below)
    uint32_t r0 = 0u, r1 = (uint32_t)(lane & 1);
    tf2x32(k0, k1, r0, r1);
    const uint32_t n0 = (uint32_t)__builtin_amdgcn_readlane((int)r0, 0);
    const uint32_t n1 = (uint32_t)__builtin_amdgcn_readlane((int)r1, 0);
    const uint32_t s0 = (uint32_t)__builtin_amdgcn_readlane((int)r0, 1);
    const uint32_t s1 = (uint32_t)__builtin_amdgcn_readlane((int)r1, 1);
    uint32_t x0 = 0u, x1 = (uint32_t)lane;
    tf2x32(s0, s1, x0, x1);
    const uint32_t bits = x0 ^ x1;
    k0 = n0; k1 = n1;
    float u = __uint_as_float(0x3f800000u | (bits >> 9)) - 1.0f;
    u = fmaxf(u + TINY, TINY);
    const float gum = -flog(-flog(u));

    // ---- hoisted LSTM1 recurrent partial (depends only on prev h1v)
    float rA0=0.f, rA1=0.f, rA2=0.f, rA3=0.f;
    float rB0=0.f, rB1=0.f, rB2=0.f, rB3=0.f;
    H_DOT(rA0, rA1, rA2, rA3, h1v, Wl[3], lane)
    H_DOT(rB0, rB1, rB2, rB3, h1v, Wl[3], rB)

    // ---- LSTM0: x-part packed (xq regs), h-part readlane(prev h0v)
    {
      v2f xA01 = {0.f,0.f}, xA23 = {0.f,0.f};
      v2f xB01 = {0.f,0.f}, xB23 = {0.f,0.f};
      float hA0=0.f,hA1=0.f,hA2=0.f,hA3=0.f;
      float hB0=0.f,hB1=0.f,hB2=0.f,hB3=0.f;
#pragma unroll
      for (int q = 0; q < 8; ++q) {
        const float4 wiA = Wl[0][q][lane];
        const float4 wiB = Wl[0][q][rB];
        const float4 x4  = xq[q];
        xA01 = pkfma(v2f{x4.x, x4.y}, v2f{wiA.x, wiA.y}, xA01);
        xA23 = pkfma(v2f{x4.z, x4.w}, v2f{wiA.z, wiA.w}, xA23);
        xB01 = pkfma(v2f{x4.x, x4.y}, v2f{wiB.x, wiB.y}, xB01);
        xB23 = pkfma(v2f{x4.z, x4.w}, v2f{wiB.z, wiB.w}, xB23);
      }
      H_DOT(hA0, hA1, hA2, hA3, h0v, Wl[1], lane)
      H_DOT(hB0, hB1, hB2, hB3, h0v, Wl[1], rB)
      const float gA = bsum0A + ((xA01.x + xA01.y) + (xA23.x + xA23.y))
                              + ((hA0 + hA1) + (hA2 + hA3));
      const float gB = bsum0B + ((xB01.x + xB01.y) + (xB23.x + xB23.y))
                              + ((hB0 + hB1) + (hB2 + hB3));
      const float oA = __shfl_xor(gA, 32, 64);
      const float oB = __shfl_xor(gB, 32, 64);
      const float ig = lo ? gA : oA, fg = lo ? oA : gA;
      const float gg = lo ? gB : oB, og = lo ? oB : gB;
      c0 = fsigmoid(fg) * c0 + fsigmoid(ig) * ftanh(gg);
      h0v = fsigmoid(og) * ftanh(c0);   // h0[lane&31] in every lane
    }

    // ---- LSTM1: x-part = readlane(new h0v), + hoisted recurrent partial
    {
      H_DOT(rA0, rA1, rA2, rA3, h0v, Wl[2], lane)
      H_DOT(rB0, rB1, rB2, rB3, h0v, Wl[2], rB)
      const float gA = bsum1A + ((rA0 + rA1) + (rA2 + rA3));
      const float gB = bsum1B + ((rB0 + rB1) + (rB2 + rB3));
      const float oA = __shfl_xor(gA, 32, 64);
      const float oB = __shfl_xor(gB, 32, 64);
      const float ig = lo ? gA : oA, fg = lo ? oA : gA;
      const float gg = lo ? gB : oB, og = lo ? oB : gB;
      c1 = fsigmoid(fg) * c1 + fsigmoid(ig) * ftanh(gg);
      h1v = fsigmoid(og) * ftanh(c1);
    }

    // ---- logits (lane = op index): readlane(h1v) against register W_pred
    float p0=0.f, p1=0.f, p2=0.f, p3=0.f;
#pragma unroll
    for (int q = 0; q < 8; ++q) {
      const float4 w = wp4[q];
      p0 = fmaf(rdlane(h1v, 4*q+0), w.x, p0);
      p1 = fmaf(rdlane(h1v, 4*q+1), w.y, p1);
      p2 = fmaf(rdlane(h1v, 4*q+2), w.z, p2);
      p3 = fmaf(rdlane(h1v, 4*q+3), w.w, p3);
    }
    const float pre   = bp + ((p0 + p1) + (p2 + p3));
    const float logit = 2.5f * ftanh(pre * 0.2f);   // TANH_CONST, 1/TEMP
    const float pert  = logit + gum;

    // ---- categorical: argmax via DPP-max + ballot (tie -> lowest index)
    const float M = wave_max64(pert);
    const unsigned long long msk = __ballot(pert == M);
    const int idxu = __ffsll((long long)msk) - 1;   // uniform

    // ---- next-step x from LDS embd (uniform addr, no vmcnt on chain)
#pragma unroll
    for (int q = 0; q < 8; ++q)
      xq[q] = *reinterpret_cast<const float4*>(&embd_lds[idxu * H + 4 * q]);

    // ---- log-softmax stats, no max-shift (logit in [-2.5,2.5])
    const float e  = fexp(logit);
    const float E  = wave_sum64(e);
    const float ES = wave_sum64(e * logit);
    const float lse = flog(E);
    const float li  = rdlane(logit, idxu);
    lp_sum  += li - lse;
    ent_sum += lse - ES / E;

    // ---- record sampled index: uniform addr+data LDS write (no branch)
    arch_lds[t] = (float)idxu;
  }

  // coalesced arch writeback
  out[2 + lane]      = arch_lds[lane];
  out[2 + 64 + lane] = arch_lds[64 + lane];
  if (lane == 0) { out[0] = lp_sum; out[1] = ent_sum; }
}

}  // namespace

extern "C" void kernel_launch(void* const* d_in, const int* in_sizes, int n_in,
                              void* d_out, int out_size, void* d_ws, size_t ws_size,
                              hipStream_t stream) {
  (void)in_sizes; (void)n_in; (void)d_ws; (void)ws_size; (void)out_size;
  const float* input_vars = (const float*)d_in[0];
  const float* W_ih0 = (const float*)d_in[1];
  const float* W_hh0 = (const float*)d_in[2];
  const float* b_ih0 = (const float*)d_in[3];
  const float* b_hh0 = (const float*)d_in[4];
  const float* W_ih1 = (const float*)d_in[5];
  const float* W_hh1 = (const float*)d_in[6];
  const float* b_ih1 = (const float*)d_in[7];
  const float* b_hh1 = (const float*)d_in[8];
  const float* embd  = (const float*)d_in[9];
  const float* W_pred = (const float*)d_in[10];
  const float* b_pred = (const float*)d_in[11];
  float* out = (float*)d_out;

  hipLaunchKernelGGL(ctrl_kernel, dim3(1), dim3(64), 0, stream,
                     input_vars, W_ih0, W_hh0, b_ih0, b_hh0,
                     W_ih1, W_hh1, b_ih1, b_hh1,
                     embd, W_pred, b_pred, out);
}